// Round 11
// baseline (453.223 us; speedup 1.0000x reference)
//
#include <hip/hip_runtime.h>
#include <stdint.h>

typedef __bf16 bf16_t;
typedef bf16_t bf16x8 __attribute__((ext_vector_type(8)));
typedef bf16_t bf16x4 __attribute__((ext_vector_type(4)));
typedef bf16_t bf16x2 __attribute__((ext_vector_type(2)));
typedef float  f32x4  __attribute__((ext_vector_type(4)));

typedef __attribute__((address_space(3))) void* as3p;
typedef const __attribute__((address_space(1))) void* as1p;

#define IN_C 512
#define HID  256
#define OUTC 128

// ---------------- prep: W transposes + cnt zero + format detect ----------
__global__ void k_prep(const float* __restrict__ W1, const float* __restrict__ W2,
                       const void* __restrict__ ei, int* __restrict__ flag,
                       int* __restrict__ cnt, bf16_t* __restrict__ W1t,
                       bf16_t* __restrict__ W2t, int n) {
  int t = blockIdx.x * blockDim.x + threadIdx.x;
  if (t < IN_C * HID) {
    W1t[(size_t)(t & 255) * IN_C + (t >> 8)] = (bf16_t)W1[t];
    return;
  }
  int u = t - IN_C * HID;
  if (u < HID * OUTC) {
    W2t[(size_t)(u & 127) * HID + (u >> 7)] = (bf16_t)W2[u];
    return;
  }
  u -= HID * OUTC;
  if (u < n) {
    cnt[u] = 0;
    return;
  }
  if (u == n) {
    const long long* p = (const long long*)ei;
    int ok = 1;
    for (int i = 0; i < 64; ++i) {
      long long v = p[i];
      if (v < 0 || v >= n) ok = 0;
    }
    *flag = ok;  // 1 => int64 layout, 0 => int32 layout
  }
}

__global__ void k_hist(const void* __restrict__ ei, const int* __restrict__ flag,
                       int* __restrict__ cnt, int E) {
  int e = blockIdx.x * blockDim.x + threadIdx.x;
  if (e >= E) return;
  int d;
  if (*flag) d = (int)((const long long*)ei)[(size_t)E + e];
  else       d = ((const int*)ei)[E + e];
  atomicAdd(&cnt[d], 1);
}

// ---------------- CSR build ----------------
__global__ void k_scan1(const int* __restrict__ cnt, int* __restrict__ ex,
                        int* __restrict__ part, float* __restrict__ dinv, int n) {
  __shared__ int sh[256];
  int i = blockIdx.x * 256 + threadIdx.x;
  int v = (i < n) ? cnt[i] : 0;
  if (i < n) dinv[i] = rsqrtf((float)v + 1.0f);  // +1 self-loop
  sh[threadIdx.x] = v;
  __syncthreads();
  int val = v;
  for (int off = 1; off < 256; off <<= 1) {
    int t = (threadIdx.x >= off) ? sh[threadIdx.x - off] : 0;
    __syncthreads();
    val += t;
    sh[threadIdx.x] = val;
    __syncthreads();
  }
  if (i < n) ex[i] = val - v;
  if (threadIdx.x == 255) part[blockIdx.x] = val;
}

__global__ void k_scan23(int* __restrict__ rs, const int* __restrict__ part,
                         int* __restrict__ cur, int n, int Etot) {
  __shared__ int sh[256];
  const int b = blockIdx.x, t = threadIdx.x;
  int p = 0;
  for (int j = t; j < b; j += 256) p += part[j];
  sh[t] = p;
  __syncthreads();
  for (int off = 128; off > 0; off >>= 1) {
    if (t < off) sh[t] += sh[t + off];
    __syncthreads();
  }
  int base = sh[0];
  int i = b * 256 + t;
  if (i < n) {
    int r = rs[i] + base;
    rs[i] = r;
    cur[i] = r;
  }
  if (i == 0) rs[n] = Etot;
}

__global__ void k_fill(const void* __restrict__ ei, const int* __restrict__ flag,
                       int* __restrict__ cur, int2* __restrict__ csrw,
                       const float* __restrict__ dinv, int E) {
  int e = blockIdx.x * blockDim.x + threadIdx.x;
  if (e >= E) return;
  int s, d;
  if (*flag) {
    const long long* p = (const long long*)ei;
    s = (int)p[e];
    d = (int)p[(size_t)E + e];
  } else {
    const int* p = (const int*)ei;
    s = p[e];
    d = p[E + e];
  }
  int pos = atomicAdd(&cur[d], 1);
  int2 v;
  v.x = s;
  v.y = __float_as_int(dinv[s]);
  csrw[pos] = v;
}

// ---------------- layer-1 GEMM, fused f32->bf16 cast on A -----------------
__global__ __launch_bounds__(512, 2) void k_gemm1(const float* __restrict__ A,
                                                  const bf16_t* __restrict__ Bt,
                                                  bf16_t* __restrict__ C, int n) {
  __shared__ float  As[128 * 32];   // 16 KB, chunk-swizzled
  __shared__ bf16_t Bs[256 * 32];   // 16 KB, chunk-swizzled
  const int bm = blockIdx.x;
  const int tid = threadIdx.x;
  const int wave = tid >> 6, lane = tid & 63;
  const int wm = (wave >> 2) * 64, wn = (wave & 3) * 64;
  const int quad = lane >> 4, l16 = lane & 15;
  const int rowclamp = n - 1;

  f32x4 acc[4][4];
#pragma unroll
  for (int i = 0; i < 4; ++i)
#pragma unroll
    for (int j = 0; j < 4; ++j)
#pragma unroll
      for (int r = 0; r < 4; ++r) acc[i][j][r] = 0.0f;

  for (int kk = 0; kk < IN_C; kk += 32) {
#pragma unroll
    for (int i = 0; i < 2; ++i) {
      int g = i * 512 + tid;
      int rat = g >> 3, ca = g & 7;
      int garow = bm * 128 + rat;
      if (garow > rowclamp) garow = rowclamp;
      const float* srcA = A + (size_t)garow * IN_C + kk + ((ca ^ (rat & 7)) << 2);
      __builtin_amdgcn_global_load_lds((as1p)srcA,
                                       (as3p)(As + (size_t)(i * 512 + wave * 64) * 4), 16, 0, 0);
      int rbt = g >> 2, cb = g & 3;
      const bf16_t* srcB = Bt + (size_t)rbt * IN_C + kk + ((cb ^ ((rbt >> 1) & 3)) << 3);
      __builtin_amdgcn_global_load_lds((as1p)srcB,
                                       (as3p)(Bs + (size_t)(i * 512 + wave * 64) * 8), 16, 0, 0);
    }
    __syncthreads();
    bf16x8 af[4], bfr[4];
#pragma unroll
    for (int i = 0; i < 4; ++i) {
      int ra = wm + i * 16 + l16;
      const float* base = As + ra * 32;
      int s = ra & 7;
      f32x4 v0 = *(const f32x4*)(base + (((quad * 2) ^ s) << 2));
      f32x4 v1 = *(const f32x4*)(base + (((quad * 2 + 1) ^ s) << 2));
      bf16x8 a;
      a[0] = (bf16_t)v0[0]; a[1] = (bf16_t)v0[1]; a[2] = (bf16_t)v0[2]; a[3] = (bf16_t)v0[3];
      a[4] = (bf16_t)v1[0]; a[5] = (bf16_t)v1[1]; a[6] = (bf16_t)v1[2]; a[7] = (bf16_t)v1[3];
      af[i] = a;
    }
#pragma unroll
    for (int j = 0; j < 4; ++j) {
      int rb = wn + j * 16 + l16;
      bfr[j] = *(const bf16x8*)(Bs + rb * 32 + ((quad ^ ((rb >> 1) & 3)) << 3));
    }
#pragma unroll
    for (int i = 0; i < 4; ++i)
#pragma unroll
      for (int j = 0; j < 4; ++j)
        acc[i][j] = __builtin_amdgcn_mfma_f32_16x16x32_bf16(af[i], bfr[j], acc[i][j], 0, 0, 0);
    __syncthreads();
  }

#pragma unroll
  for (int i = 0; i < 4; ++i) {
#pragma unroll
    for (int j = 0; j < 4; ++j) {
      int col = wn + j * 16 + l16;
      int row0 = bm * 128 + wm + i * 16 + quad * 4;
#pragma unroll
      for (int r = 0; r < 4; ++r)
        C[(size_t)(row0 + r) * HID + col] = (bf16_t)acc[i][j][r];
    }
  }
}

// ---------------- bf16 MFMA GEMM (layer 2, m97 structure) -----------------
__global__ __launch_bounds__(256, 3) void k_gemm(const bf16_t* __restrict__ A,
                                                 const bf16_t* __restrict__ Bt,
                                                 bf16_t* __restrict__ C,
                                                 int Kdim, int Ncols) {
  __shared__ bf16_t As[128 * 32];
  __shared__ bf16_t Bs[128 * 32];
  const int bm = blockIdx.x, bn = blockIdx.y;
  const int tid = threadIdx.x;
  const int wave = tid >> 6, lane = tid & 63;
  const int wm = (wave >> 1) * 64, wn = (wave & 1) * 64;
  const int quad = lane >> 4, l16 = lane & 15;

  const size_t abase = (size_t)bm * 128 * Kdim;
  const size_t bbase = (size_t)bn * 128 * Kdim;

  f32x4 acc[4][4];
#pragma unroll
  for (int i = 0; i < 4; ++i)
#pragma unroll
    for (int j = 0; j < 4; ++j)
#pragma unroll
      for (int r = 0; r < 4; ++r) acc[i][j][r] = 0.0f;

  for (int kk = 0; kk < Kdim; kk += 32) {
#pragma unroll
    for (int i = 0; i < 2; ++i) {
      int g = i * 256 + tid;
      int row = g >> 2, col = (g & 3) * 8;
      const bf16_t* ga = A + abase + (size_t)row * Kdim + kk + col;
      __builtin_amdgcn_global_load_lds((as1p)ga,
                                       (as3p)(&As[(i * 256 + wave * 64) * 8]), 16, 0, 0);
      const bf16_t* gb = Bt + bbase + (size_t)row * Kdim + kk + col;
      __builtin_amdgcn_global_load_lds((as1p)gb,
                                       (as3p)(&Bs[(i * 256 + wave * 64) * 8]), 16, 0, 0);
    }
    __syncthreads();
    bf16x8 af[4], bf[4];
#pragma unroll
    for (int i = 0; i < 4; ++i)
      af[i] = *(const bf16x8*)(&As[(wm + i * 16 + l16) * 32 + quad * 8]);
#pragma unroll
    for (int j = 0; j < 4; ++j)
      bf[j] = *(const bf16x8*)(&Bs[(wn + j * 16 + l16) * 32 + quad * 8]);
#pragma unroll
    for (int i = 0; i < 4; ++i)
#pragma unroll
      for (int j = 0; j < 4; ++j)
        acc[i][j] = __builtin_amdgcn_mfma_f32_16x16x32_bf16(af[i], bf[j], acc[i][j], 0, 0, 0);
    __syncthreads();
  }

#pragma unroll
  for (int i = 0; i < 4; ++i) {
#pragma unroll
    for (int j = 0; j < 4; ++j) {
      int col = bn * 128 + wn + j * 16 + l16;
      int row0 = bm * 128 + wm + i * 16 + quad * 4;
#pragma unroll
      for (int r = 0; r < 4; ++r)
        C[(size_t)(row0 + r) * Ncols + col] = (bf16_t)acc[i][j][r];
    }
  }
}

// ---------------- layer-1 aggregation: XCD-sliced features ---------------
// slice = blockIdx & 7 -> lands on one XCD (round-robin dispatch); slice s
// handles features [s*32, s*32+32) = exactly one 64B line per H row. Each
// line is then fetched by exactly ONE XCD (compulsory 25.6 MB vs ~7x), and
// the per-slice working set (3.2 MB) becomes L2-resident. Block = 4 waves
// x 8 dsts = 32 dsts. Per edge: 16 lanes x bf16x2; 32 edges in flight.
__global__ void k_agg_l1(const bf16_t* __restrict__ H, const int* __restrict__ rs,
                         const int2* __restrict__ csrw, const float* __restrict__ dinv,
                         const float* __restrict__ b1, bf16_t* __restrict__ R,
                         int n, int mpad) {
  const int slice = blockIdx.x & 7;
  const int group = blockIdx.x >> 3;
  const int wave = threadIdx.x >> 6;
  const int lane = threadIdx.x & 63;
  const int q = (lane >> 4) & 3;   // edge slot within quad
  const int fl = lane & 15;        // feature pair (2 bf16)
  const int c0 = slice * 32;
  const bf16_t* Hc = H + c0 + fl * 2;
  for (int i = 0; i < 8; ++i) {
    int d = group * 32 + wave * 8 + i;
    if (d >= mpad) return;
    if (d >= n) {
      if (q == 0) {
        bf16x2 z;
        z[0] = (bf16_t)0.0f; z[1] = (bf16_t)0.0f;
        *(bf16x2*)(R + (size_t)d * HID + c0 + fl * 2) = z;
      }
      continue;
    }
    int e0 = rs[d], e1 = rs[d + 1];
    float p0 = 0.f, p1 = 0.f, r0 = 0.f, r1 = 0.f;
    for (int e = e0; e < e1; e += 32) {
      int2 cw[8];
      float w[8];
      bf16x2 h[8];
#pragma unroll
      for (int u = 0; u < 8; ++u) {
        int idx = e + 4 * u + q;
        int ce = idx < e1 ? idx : e1 - 1;
        cw[u] = csrw[ce];
        w[u] = idx < e1 ? __int_as_float(cw[u].y) : 0.0f;
      }
#pragma unroll
      for (int u = 0; u < 8; ++u)
        h[u] = *(const bf16x2*)(Hc + (size_t)cw[u].x * HID);
#pragma unroll
      for (int u = 0; u < 8; ++u) {
        if (u & 1) { r0 += w[u] * (float)h[u][0]; r1 += w[u] * (float)h[u][1]; }
        else       { p0 += w[u] * (float)h[u][0]; p1 += w[u] * (float)h[u][1]; }
      }
    }
    float f0 = p0 + r0, f1 = p1 + r1;
    f0 += __shfl_xor(f0, 16); f1 += __shfl_xor(f1, 16);
    f0 += __shfl_xor(f0, 32); f1 += __shfl_xor(f1, 32);
    float dd = dinv[d];
    float dv2 = dd * dd;
    bf16x2 hs = *(const bf16x2*)(Hc + (size_t)d * HID);
    float2 bb = ((const float2*)b1)[slice * 16 + fl];
    float v0 = fmaxf(f0 * dd + dv2 * (float)hs[0] + bb.x, 0.f);
    float v1 = fmaxf(f1 * dd + dv2 * (float)hs[1] + bb.y, 0.f);
    bf16x2 o;
    o[0] = (bf16_t)v0; o[1] = (bf16_t)v1;
    if (q == 0)
      *(bf16x2*)(R + (size_t)d * HID + c0 + fl * 2) = o;
  }
}

// ---------------- layer-2 aggregation: XCD-sliced features (4 slices) -----
// OUTC=128 -> 4 slices of 32 features (one 64B line each); slice =
// blockIdx & 3 -> each slice on 2 XCDs (<=2x fetch, 3.2 MB L2-resident).
__global__ void k_agg_l2(const bf16_t* __restrict__ H, const int* __restrict__ rs,
                         const int2* __restrict__ csrw, const float* __restrict__ dinv,
                         const float* __restrict__ b2, float* __restrict__ out, int n) {
  const int slice = blockIdx.x & 3;
  const int group = blockIdx.x >> 2;
  const int wave = threadIdx.x >> 6;
  const int lane = threadIdx.x & 63;
  const int q = (lane >> 4) & 3;
  const int fl = lane & 15;
  const int c0 = slice * 32;
  const bf16_t* Hc = H + c0 + fl * 2;
  for (int i = 0; i < 8; ++i) {
    int d = group * 32 + wave * 8 + i;
    if (d >= n) return;
    int e0 = rs[d], e1 = rs[d + 1];
    float p0 = 0.f, p1 = 0.f, r0 = 0.f, r1 = 0.f;
    for (int e = e0; e < e1; e += 32) {
      int2 cw[8];
      float w[8];
      bf16x2 h[8];
#pragma unroll
      for (int u = 0; u < 8; ++u) {
        int idx = e + 4 * u + q;
        int ce = idx < e1 ? idx : e1 - 1;
        cw[u] = csrw[ce];
        w[u] = idx < e1 ? __int_as_float(cw[u].y) : 0.0f;
      }
#pragma unroll
      for (int u = 0; u < 8; ++u)
        h[u] = *(const bf16x2*)(Hc + (size_t)cw[u].x * OUTC);
#pragma unroll
      for (int u = 0; u < 8; ++u) {
        if (u & 1) { r0 += w[u] * (float)h[u][0]; r1 += w[u] * (float)h[u][1]; }
        else       { p0 += w[u] * (float)h[u][0]; p1 += w[u] * (float)h[u][1]; }
      }
    }
    float f0 = p0 + r0, f1 = p1 + r1;
    f0 += __shfl_xor(f0, 16); f1 += __shfl_xor(f1, 16);
    f0 += __shfl_xor(f0, 32); f1 += __shfl_xor(f1, 32);
    float dd = dinv[d];
    float dv2 = dd * dd;
    bf16x2 hs = *(const bf16x2*)(Hc + (size_t)d * OUTC);
    float2 bb = ((const float2*)b2)[slice * 16 + fl];
    float2 o;
    o.x = f0 * dd + dv2 * (float)hs[0] + bb.x;
    o.y = f1 * dd + dv2 * (float)hs[1] + bb.y;
    if (q == 0)
      ((float2*)(out + (size_t)d * OUTC + c0))[fl] = o;
  }
}

// ---------------- launch ----------------
extern "C" void kernel_launch(void* const* d_in, const int* in_sizes, int n_in,
                              void* d_out, int out_size, void* d_ws, size_t ws_size,
                              hipStream_t stream) {
  const float* x  = (const float*)d_in[0];
  const void*  ei = d_in[1];
  const float* W1 = (const float*)d_in[2];
  const float* b1 = (const float*)d_in[3];
  const float* W2 = (const float*)d_in[4];
  const float* b2 = (const float*)d_in[5];

  const int n = in_sizes[0] / IN_C;    // 50000
  const int E = in_sizes[1] / 2;       // 800000
  const int mpad = (n + 127) & ~127;   // 50048

  char* w = (char*)d_ws;
  size_t off = 0;
  auto alloc = [&](size_t bytes) -> void* {
    void* p = w + off;
    off = (off + bytes + 255) & ~(size_t)255;
    return p;
  };

  int*    flag = (int*)alloc(4);
  int*    cnt  = (int*)alloc((size_t)n * 4);
  float*  dinv = (float*)alloc((size_t)n * 4);
  int*    rs   = (int*)alloc((size_t)(n + 1) * 4);
  int*    cur  = (int*)alloc((size_t)n * 4);
  int*    part = (int*)alloc(1024);
  int2*   csrw = (int2*)alloc((size_t)E * 8);
  bf16_t* W1t  = (bf16_t*)alloc((size_t)HID * IN_C * 2);
  bf16_t* W2t  = (bf16_t*)alloc((size_t)OUTC * HID * 2);
  bf16_t* H1b  = (bf16_t*)alloc((size_t)mpad * HID * 2);
  bf16_t* R1b  = (bf16_t*)alloc((size_t)mpad * HID * 2);
  bf16_t* H2b  = (bf16_t*)alloc((size_t)mpad * OUTC * 2);
  (void)ws_size; (void)n_in; (void)out_size;

  const int nb = (n + 255) / 256;
  const int prepT = IN_C * HID + HID * OUTC + n + 1;

  k_prep<<<(prepT + 255) / 256, 256, 0, stream>>>(W1, W2, ei, flag, cnt, W1t, W2t, n);
  k_hist<<<(E + 255) / 256, 256, 0, stream>>>(ei, flag, cnt, E);
  k_scan1<<<nb, 256, 0, stream>>>(cnt, rs, part, dinv, n);
  k_scan23<<<nb, 256, 0, stream>>>(rs, part, cur, n, E);
  k_fill<<<(E + 255) / 256, 256, 0, stream>>>(ei, flag, cur, csrw, dinv, E);

  k_gemm1<<<mpad / 128, 512, 0, stream>>>(x, W1t, H1b, n);
  k_agg_l1<<<8 * ((mpad + 31) / 32), 256, 0, stream>>>(H1b, rs, csrw, dinv, b1, R1b, n, mpad);
  k_gemm<<<dim3(mpad / 128, 1), 256, 0, stream>>>(R1b, W2t, H2b, HID, OUTC);
  k_agg_l2<<<4 * ((n + 31) / 32), 256, 0, stream>>>(H2b, rs, csrw, dinv, b2, (float*)d_out, n);
}

// Round 12
// 366.860 us; speedup vs baseline: 1.2354x; 1.2354x over previous
//
#include <hip/hip_runtime.h>
#include <stdint.h>

typedef __bf16 bf16_t;
typedef bf16_t bf16x8 __attribute__((ext_vector_type(8)));
typedef bf16_t bf16x4 __attribute__((ext_vector_type(4)));
typedef bf16_t bf16x2 __attribute__((ext_vector_type(2)));
typedef float  f32x4  __attribute__((ext_vector_type(4)));

typedef __attribute__((address_space(3))) void* as3p;
typedef const __attribute__((address_space(1))) void* as1p;

#define IN_C 512
#define HID  256
#define OUTC 128

// ---------------- prep: W transposes + cnt zero + format detect ----------
__global__ void k_prep(const float* __restrict__ W1, const float* __restrict__ W2,
                       const void* __restrict__ ei, int* __restrict__ flag,
                       int* __restrict__ cnt, bf16_t* __restrict__ W1t,
                       bf16_t* __restrict__ W2t, int n) {
  int t = blockIdx.x * blockDim.x + threadIdx.x;
  if (t < IN_C * HID) {
    W1t[(size_t)(t & 255) * IN_C + (t >> 8)] = (bf16_t)W1[t];
    return;
  }
  int u = t - IN_C * HID;
  if (u < HID * OUTC) {
    W2t[(size_t)(u & 127) * HID + (u >> 7)] = (bf16_t)W2[u];
    return;
  }
  u -= HID * OUTC;
  if (u < n) {
    cnt[u] = 0;
    return;
  }
  if (u == n) {
    const long long* p = (const long long*)ei;
    int ok = 1;
    for (int i = 0; i < 64; ++i) {
      long long v = p[i];
      if (v < 0 || v >= n) ok = 0;
    }
    *flag = ok;  // 1 => int64 layout, 0 => int32 layout
  }
}

__global__ void k_hist(const void* __restrict__ ei, const int* __restrict__ flag,
                       int* __restrict__ cnt, int E) {
  int e = blockIdx.x * blockDim.x + threadIdx.x;
  if (e >= E) return;
  int d;
  if (*flag) d = (int)((const long long*)ei)[(size_t)E + e];
  else       d = ((const int*)ei)[E + e];
  atomicAdd(&cnt[d], 1);
}

// ---------------- CSR build ----------------
__global__ void k_scan1(const int* __restrict__ cnt, int* __restrict__ ex,
                        int* __restrict__ part, float* __restrict__ dinv, int n) {
  __shared__ int sh[256];
  int i = blockIdx.x * 256 + threadIdx.x;
  int v = (i < n) ? cnt[i] : 0;
  if (i < n) dinv[i] = rsqrtf((float)v + 1.0f);  // +1 self-loop
  sh[threadIdx.x] = v;
  __syncthreads();
  int val = v;
  for (int off = 1; off < 256; off <<= 1) {
    int t = (threadIdx.x >= off) ? sh[threadIdx.x - off] : 0;
    __syncthreads();
    val += t;
    sh[threadIdx.x] = val;
    __syncthreads();
  }
  if (i < n) ex[i] = val - v;
  if (threadIdx.x == 255) part[blockIdx.x] = val;
}

__global__ void k_scan23(int* __restrict__ rs, const int* __restrict__ part,
                         int* __restrict__ cur, int n, int Etot) {
  __shared__ int sh[256];
  const int b = blockIdx.x, t = threadIdx.x;
  int p = 0;
  for (int j = t; j < b; j += 256) p += part[j];
  sh[t] = p;
  __syncthreads();
  for (int off = 128; off > 0; off >>= 1) {
    if (t < off) sh[t] += sh[t + off];
    __syncthreads();
  }
  int base = sh[0];
  int i = b * 256 + t;
  if (i < n) {
    int r = rs[i] + base;
    rs[i] = r;
    cur[i] = r;
  }
  if (i == 0) rs[n] = Etot;
}

__global__ void k_fill(const void* __restrict__ ei, const int* __restrict__ flag,
                       int* __restrict__ cur, int2* __restrict__ csrw,
                       const float* __restrict__ dinv, int E) {
  int e = blockIdx.x * blockDim.x + threadIdx.x;
  if (e >= E) return;
  int s, d;
  if (*flag) {
    const long long* p = (const long long*)ei;
    s = (int)p[e];
    d = (int)p[(size_t)E + e];
  } else {
    const int* p = (const int*)ei;
    s = p[e];
    d = p[E + e];
  }
  int pos = atomicAdd(&cur[d], 1);
  int2 v;
  v.x = s;
  v.y = __float_as_int(dinv[s]);
  csrw[pos] = v;
}

// ---------------- layer-1 GEMM, fused f32->bf16 cast on A -----------------
__global__ __launch_bounds__(512, 2) void k_gemm1(const float* __restrict__ A,
                                                  const bf16_t* __restrict__ Bt,
                                                  bf16_t* __restrict__ C, int n) {
  __shared__ float  As[128 * 32];   // 16 KB, chunk-swizzled
  __shared__ bf16_t Bs[256 * 32];   // 16 KB, chunk-swizzled
  const int bm = blockIdx.x;
  const int tid = threadIdx.x;
  const int wave = tid >> 6, lane = tid & 63;
  const int wm = (wave >> 2) * 64, wn = (wave & 3) * 64;
  const int quad = lane >> 4, l16 = lane & 15;
  const int rowclamp = n - 1;

  f32x4 acc[4][4];
#pragma unroll
  for (int i = 0; i < 4; ++i)
#pragma unroll
    for (int j = 0; j < 4; ++j)
#pragma unroll
      for (int r = 0; r < 4; ++r) acc[i][j][r] = 0.0f;

  for (int kk = 0; kk < IN_C; kk += 32) {
#pragma unroll
    for (int i = 0; i < 2; ++i) {
      int g = i * 512 + tid;
      int rat = g >> 3, ca = g & 7;
      int garow = bm * 128 + rat;
      if (garow > rowclamp) garow = rowclamp;
      const float* srcA = A + (size_t)garow * IN_C + kk + ((ca ^ (rat & 7)) << 2);
      __builtin_amdgcn_global_load_lds((as1p)srcA,
                                       (as3p)(As + (size_t)(i * 512 + wave * 64) * 4), 16, 0, 0);
      int rbt = g >> 2, cb = g & 3;
      const bf16_t* srcB = Bt + (size_t)rbt * IN_C + kk + ((cb ^ ((rbt >> 1) & 3)) << 3);
      __builtin_amdgcn_global_load_lds((as1p)srcB,
                                       (as3p)(Bs + (size_t)(i * 512 + wave * 64) * 8), 16, 0, 0);
    }
    __syncthreads();
    bf16x8 af[4], bfr[4];
#pragma unroll
    for (int i = 0; i < 4; ++i) {
      int ra = wm + i * 16 + l16;
      const float* base = As + ra * 32;
      int s = ra & 7;
      f32x4 v0 = *(const f32x4*)(base + (((quad * 2) ^ s) << 2));
      f32x4 v1 = *(const f32x4*)(base + (((quad * 2 + 1) ^ s) << 2));
      bf16x8 a;
      a[0] = (bf16_t)v0[0]; a[1] = (bf16_t)v0[1]; a[2] = (bf16_t)v0[2]; a[3] = (bf16_t)v0[3];
      a[4] = (bf16_t)v1[0]; a[5] = (bf16_t)v1[1]; a[6] = (bf16_t)v1[2]; a[7] = (bf16_t)v1[3];
      af[i] = a;
    }
#pragma unroll
    for (int j = 0; j < 4; ++j) {
      int rb = wn + j * 16 + l16;
      bfr[j] = *(const bf16x8*)(Bs + rb * 32 + ((quad ^ ((rb >> 1) & 3)) << 3));
    }
#pragma unroll
    for (int i = 0; i < 4; ++i)
#pragma unroll
      for (int j = 0; j < 4; ++j)
        acc[i][j] = __builtin_amdgcn_mfma_f32_16x16x32_bf16(af[i], bfr[j], acc[i][j], 0, 0, 0);
    __syncthreads();
  }

#pragma unroll
  for (int i = 0; i < 4; ++i) {
#pragma unroll
    for (int j = 0; j < 4; ++j) {
      int col = wn + j * 16 + l16;
      int row0 = bm * 128 + wm + i * 16 + quad * 4;
#pragma unroll
      for (int r = 0; r < 4; ++r)
        C[(size_t)(row0 + r) * HID + col] = (bf16_t)acc[i][j][r];
    }
  }
}

// ---------------- bf16 MFMA GEMM (layer 2, m97 structure) -----------------
__global__ __launch_bounds__(256, 3) void k_gemm(const bf16_t* __restrict__ A,
                                                 const bf16_t* __restrict__ Bt,
                                                 bf16_t* __restrict__ C,
                                                 int Kdim, int Ncols) {
  __shared__ bf16_t As[128 * 32];
  __shared__ bf16_t Bs[128 * 32];
  const int bm = blockIdx.x, bn = blockIdx.y;
  const int tid = threadIdx.x;
  const int wave = tid >> 6, lane = tid & 63;
  const int wm = (wave >> 1) * 64, wn = (wave & 1) * 64;
  const int quad = lane >> 4, l16 = lane & 15;

  const size_t abase = (size_t)bm * 128 * Kdim;
  const size_t bbase = (size_t)bn * 128 * Kdim;

  f32x4 acc[4][4];
#pragma unroll
  for (int i = 0; i < 4; ++i)
#pragma unroll
    for (int j = 0; j < 4; ++j)
#pragma unroll
      for (int r = 0; r < 4; ++r) acc[i][j][r] = 0.0f;

  for (int kk = 0; kk < Kdim; kk += 32) {
#pragma unroll
    for (int i = 0; i < 2; ++i) {
      int g = i * 256 + tid;
      int row = g >> 2, col = (g & 3) * 8;
      const bf16_t* ga = A + abase + (size_t)row * Kdim + kk + col;
      __builtin_amdgcn_global_load_lds((as1p)ga,
                                       (as3p)(&As[(i * 256 + wave * 64) * 8]), 16, 0, 0);
      const bf16_t* gb = Bt + bbase + (size_t)row * Kdim + kk + col;
      __builtin_amdgcn_global_load_lds((as1p)gb,
                                       (as3p)(&Bs[(i * 256 + wave * 64) * 8]), 16, 0, 0);
    }
    __syncthreads();
    bf16x8 af[4], bf[4];
#pragma unroll
    for (int i = 0; i < 4; ++i)
      af[i] = *(const bf16x8*)(&As[(wm + i * 16 + l16) * 32 + quad * 8]);
#pragma unroll
    for (int j = 0; j < 4; ++j)
      bf[j] = *(const bf16x8*)(&Bs[(wn + j * 16 + l16) * 32 + quad * 8]);
#pragma unroll
    for (int i = 0; i < 4; ++i)
#pragma unroll
      for (int j = 0; j < 4; ++j)
        acc[i][j] = __builtin_amdgcn_mfma_f32_16x16x32_bf16(af[i], bf[j], acc[i][j], 0, 0, 0);
    __syncthreads();
  }

#pragma unroll
  for (int i = 0; i < 4; ++i) {
#pragma unroll
    for (int j = 0; j < 4; ++j) {
      int col = bn * 128 + wn + j * 16 + l16;
      int row0 = bm * 128 + wm + i * 16 + quad * 4;
#pragma unroll
      for (int r = 0; r < 4; ++r)
        C[(size_t)(row0 + r) * Ncols + col] = (bf16_t)acc[i][j][r];
    }
  }
}

// ---------------- layer-1 aggregation: half-wave rows, 16 edges in flight --
// Round-8 best: 4 dsts / 256-thread block; each half-wave (32 lanes x bf16x8
// = 512B) services one edge per slot => 8-slot batch = 16 edges in flight.
// Tail handled by clamping OOB slots to e1-1 with weight 0.
__global__ void k_agg_l1(const bf16_t* __restrict__ H, const int* __restrict__ rs,
                         const int2* __restrict__ csrw, const float* __restrict__ dinv,
                         const float* __restrict__ b1, bf16_t* __restrict__ R,
                         int n, int mpad) {
  int d = blockIdx.x * 4 + (threadIdx.x >> 6);
  if (d >= mpad) return;
  const int lane = threadIdx.x & 63;
  const int half = lane >> 5;     // which edge of the pair
  const int fl = lane & 31;       // feature lane: features fl*8 .. fl*8+7
  if (d >= n) {
    if (lane < 32) {
      bf16x8 z;
#pragma unroll
      for (int j = 0; j < 8; ++j) z[j] = (bf16_t)0.0f;
      *(bf16x8*)(R + (size_t)d * HID + fl * 8) = z;
    }
    return;
  }
  int e0 = rs[d], e1 = rs[d + 1];
  float acc0[8], acc1[8];
#pragma unroll
  for (int j = 0; j < 8; ++j) { acc0[j] = 0.f; acc1[j] = 0.f; }
  for (int e = e0; e < e1; e += 16) {
    int2 cw[8];
    float w[8];
    bf16x8 h[8];
#pragma unroll
    for (int u = 0; u < 8; ++u) {
      int idx = e + 2 * u + half;
      int ce = idx < e1 ? idx : e1 - 1;
      cw[u] = csrw[ce];
      w[u] = idx < e1 ? __int_as_float(cw[u].y) : 0.0f;
    }
#pragma unroll
    for (int u = 0; u < 8; ++u)
      h[u] = *(const bf16x8*)(H + (size_t)cw[u].x * HID + fl * 8);
#pragma unroll
    for (int u = 0; u < 8; ++u) {
      float* A = (u & 1) ? acc1 : acc0;
#pragma unroll
      for (int j = 0; j < 8; ++j) A[j] += w[u] * (float)h[u][j];
    }
  }
  float a[8];
#pragma unroll
  for (int j = 0; j < 8; ++j) a[j] = acc0[j] + acc1[j];
#pragma unroll
  for (int j = 0; j < 8; ++j) a[j] += __shfl_xor(a[j], 32);
  float dd = dinv[d];
  float dv2 = dd * dd;
  bf16x8 hs = *(const bf16x8*)(H + (size_t)d * HID + fl * 8);
  float4 bb0 = ((const float4*)b1)[fl * 2];
  float4 bb1 = ((const float4*)b1)[fl * 2 + 1];
  float bbv[8] = {bb0.x, bb0.y, bb0.z, bb0.w, bb1.x, bb1.y, bb1.z, bb1.w};
  bf16x8 o;
#pragma unroll
  for (int j = 0; j < 8; ++j)
    o[j] = (bf16_t)fmaxf(a[j] * dd + dv2 * (float)hs[j] + bbv[j], 0.f);
  if (lane < 32)
    *(bf16x8*)(R + (size_t)d * HID + fl * 8) = o;
}

// ---------------- layer-2 aggregation: quarter-wave rows, 32 edges in flight
__global__ void k_agg_l2(const bf16_t* __restrict__ H, const int* __restrict__ rs,
                         const int2* __restrict__ csrw, const float* __restrict__ dinv,
                         const float* __restrict__ b2, float* __restrict__ out, int n) {
  int d = blockIdx.x * 4 + (threadIdx.x >> 6);
  if (d >= n) return;
  const int lane = threadIdx.x & 63;
  const int q = (lane >> 4) & 3;  // which edge of the quad
  const int fl = lane & 15;       // feature lane: features fl*8 .. fl*8+7
  int e0 = rs[d], e1 = rs[d + 1];
  float acc0[8], acc1[8];
#pragma unroll
  for (int j = 0; j < 8; ++j) { acc0[j] = 0.f; acc1[j] = 0.f; }
  for (int e = e0; e < e1; e += 32) {
    int2 cw[8];
    float w[8];
    bf16x8 h[8];
#pragma unroll
    for (int u = 0; u < 8; ++u) {
      int idx = e + 4 * u + q;
      int ce = idx < e1 ? idx : e1 - 1;
      cw[u] = csrw[ce];
      w[u] = idx < e1 ? __int_as_float(cw[u].y) : 0.0f;
    }
#pragma unroll
    for (int u = 0; u < 8; ++u)
      h[u] = *(const bf16x8*)(H + (size_t)cw[u].x * OUTC + fl * 8);
#pragma unroll
    for (int u = 0; u < 8; ++u) {
      float* A = (u & 1) ? acc1 : acc0;
#pragma unroll
      for (int j = 0; j < 8; ++j) A[j] += w[u] * (float)h[u][j];
    }
  }
  float a[8];
#pragma unroll
  for (int j = 0; j < 8; ++j) a[j] = acc0[j] + acc1[j];
#pragma unroll
  for (int j = 0; j < 8; ++j) a[j] += __shfl_xor(a[j], 16);
#pragma unroll
  for (int j = 0; j < 8; ++j) a[j] += __shfl_xor(a[j], 32);
  float dd = dinv[d];
  float dv2 = dd * dd;
  bf16x8 hs = *(const bf16x8*)(H + (size_t)d * OUTC + fl * 8);
  float4 bb0 = ((const float4*)b2)[fl * 2];
  float4 bb1 = ((const float4*)b2)[fl * 2 + 1];
  float bbv[8] = {bb0.x, bb0.y, bb0.z, bb0.w, bb1.x, bb1.y, bb1.z, bb1.w};
  float4 o0, o1;
  o0.x = a[0] * dd + dv2 * (float)hs[0] + bbv[0];
  o0.y = a[1] * dd + dv2 * (float)hs[1] + bbv[1];
  o0.z = a[2] * dd + dv2 * (float)hs[2] + bbv[2];
  o0.w = a[3] * dd + dv2 * (float)hs[3] + bbv[3];
  o1.x = a[4] * dd + dv2 * (float)hs[4] + bbv[4];
  o1.y = a[5] * dd + dv2 * (float)hs[5] + bbv[5];
  o1.z = a[6] * dd + dv2 * (float)hs[6] + bbv[6];
  o1.w = a[7] * dd + dv2 * (float)hs[7] + bbv[7];
  if (lane < 16) {
    ((float4*)(out + (size_t)d * OUTC))[fl * 2] = o0;
    ((float4*)(out + (size_t)d * OUTC))[fl * 2 + 1] = o1;
  }
}

// ---------------- launch ----------------
extern "C" void kernel_launch(void* const* d_in, const int* in_sizes, int n_in,
                              void* d_out, int out_size, void* d_ws, size_t ws_size,
                              hipStream_t stream) {
  const float* x  = (const float*)d_in[0];
  const void*  ei = d_in[1];
  const float* W1 = (const float*)d_in[2];
  const float* b1 = (const float*)d_in[3];
  const float* W2 = (const float*)d_in[4];
  const float* b2 = (const float*)d_in[5];

  const int n = in_sizes[0] / IN_C;    // 50000
  const int E = in_sizes[1] / 2;       // 800000
  const int mpad = (n + 127) & ~127;   // 50048

  char* w = (char*)d_ws;
  size_t off = 0;
  auto alloc = [&](size_t bytes) -> void* {
    void* p = w + off;
    off = (off + bytes + 255) & ~(size_t)255;
    return p;
  };

  int*    flag = (int*)alloc(4);
  int*    cnt  = (int*)alloc((size_t)n * 4);
  float*  dinv = (float*)alloc((size_t)n * 4);
  int*    rs   = (int*)alloc((size_t)(n + 1) * 4);
  int*    cur  = (int*)alloc((size_t)n * 4);
  int*    part = (int*)alloc(1024);
  int2*   csrw = (int2*)alloc((size_t)E * 8);
  bf16_t* W1t  = (bf16_t*)alloc((size_t)HID * IN_C * 2);
  bf16_t* W2t  = (bf16_t*)alloc((size_t)OUTC * HID * 2);
  bf16_t* H1b  = (bf16_t*)alloc((size_t)mpad * HID * 2);
  bf16_t* R1b  = (bf16_t*)alloc((size_t)mpad * HID * 2);
  bf16_t* H2b  = (bf16_t*)alloc((size_t)mpad * OUTC * 2);
  (void)ws_size; (void)n_in; (void)out_size;

  const int nb = (n + 255) / 256;
  const int prepT = IN_C * HID + HID * OUTC + n + 1;

  k_prep<<<(prepT + 255) / 256, 256, 0, stream>>>(W1, W2, ei, flag, cnt, W1t, W2t, n);
  k_hist<<<(E + 255) / 256, 256, 0, stream>>>(ei, flag, cnt, E);
  k_scan1<<<nb, 256, 0, stream>>>(cnt, rs, part, dinv, n);
  k_scan23<<<nb, 256, 0, stream>>>(rs, part, cur, n, E);
  k_fill<<<(E + 255) / 256, 256, 0, stream>>>(ei, flag, cur, csrw, dinv, E);

  k_gemm1<<<mpad / 128, 512, 0, stream>>>(x, W1t, H1b, n);
  k_agg_l1<<<(mpad + 3) / 4, 256, 0, stream>>>(H1b, rs, csrw, dinv, b1, R1b, n, mpad);
  k_gemm<<<dim3(mpad / 128, 1), 256, 0, stream>>>(R1b, W2t, H2b, HID, OUTC);
  k_agg_l2<<<(n + 3) / 4, 256, 0, stream>>>(H2b, rs, csrw, dinv, b2, (float*)d_out, n);
}